// Round 2
// baseline (1248.975 us; speedup 1.0000x reference)
//
#include <hip/hip_runtime.h>
#include <hip/hip_bf16.h>

// Problem constants (from reference)
constexpr int NN = 50000;   // nodes
constexpr int EE = 800000;  // edges
constexpr int C  = 128;     // channels (IN == H == 128)
constexpr int KC = 20;      // clusters

// ---------------------------------------------------------------------------
// Graph preprocessing.  NOTE: harness passes integer inputs as int32.
// ---------------------------------------------------------------------------

__global__ void k_init_deg(float* deg) {
    int i = blockIdx.x * 256 + threadIdx.x;
    if (i < NN) deg[i] = 1.0f;   // self-loop weight
}

// weighted degree + per-dst edge count (histogram) in one pass
__global__ void k_deg_hist(const int* __restrict__ ei, const float* __restrict__ ew,
                           float* deg, unsigned* cnt) {
    int e = blockIdx.x * 256 + threadIdx.x;
    if (e >= EE) return;
    int d = ei[EE + e];
    atomicAdd(&deg[d], ew[e]);
    atomicAdd(&cnt[d], 1u);
}

__global__ void k_dinv(float* deg) {
    int i = blockIdx.x * 256 + threadIdx.x;
    if (i < NN) {
        float d = deg[i];
        deg[i] = (d > 0.0f) ? rsqrtf(d) : 0.0f;
    }
}

// single-block scan: cnt[N] -> exclusive offsets in place (off == cnt), copy to cursor.
__global__ __launch_bounds__(1024) void k_scan(unsigned* off, unsigned* cursor) {
    __shared__ unsigned wsum[16];
    __shared__ unsigned wpre[16];
    int tid  = threadIdx.x;
    int lane = tid & 63;
    int wv   = tid >> 6;
    unsigned carry = 0;
    for (int base = 0; base < NN; base += 1024) {
        int idx = base + tid;
        unsigned v = (idx < NN) ? off[idx] : 0u;
        unsigned x = v;
        #pragma unroll
        for (int s = 1; s < 64; s <<= 1) {
            unsigned t = __shfl_up(x, s, 64);
            if (lane >= s) x += t;
        }
        if (lane == 63) wsum[wv] = x;
        __syncthreads();
        if (wv == 0 && lane < 16) {
            unsigned y = wsum[lane];
            #pragma unroll
            for (int s = 1; s < 16; s <<= 1) {
                unsigned t = __shfl_up(y, s, 64);
                if (lane >= s) y += t;
            }
            wpre[lane] = y - wsum[lane];  // exclusive across waves
        }
        __syncthreads();
        unsigned excl = carry + wpre[wv] + x - v;
        if (idx < NN) { off[idx] = excl; cursor[idx] = excl; }
        unsigned tot = wpre[15] + wsum[15];
        __syncthreads();          // protect wsum/wpre before next tile overwrites
        carry += tot;
    }
    if (tid == 0) off[NN] = carry;
}

// fill CSR (by dst): src id + fused gcn_norm weight
__global__ void k_fill(const int* __restrict__ ei, const float* __restrict__ ew,
                       const float* __restrict__ dinv, unsigned* cursor,
                       unsigned* __restrict__ csrc, float* __restrict__ cw) {
    int e = blockIdx.x * 256 + threadIdx.x;
    if (e >= EE) return;
    int s = ei[e];
    int d = ei[EE + e];
    unsigned p = atomicAdd(&cursor[d], 1u);
    csrc[p] = (unsigned)s;
    cw[p]   = dinv[s] * ew[e] * dinv[d];
}

// ---------------------------------------------------------------------------
// GEMM: Out[rows,128] = A[sel(r),128] @ W[128,128]   (f32 vector ALU)
// perm != nullptr -> row r reads A[perm[r]] (corruption layer); else A[r].
// ---------------------------------------------------------------------------

__global__ __launch_bounds__(256) void k_gemm(const float* __restrict__ A,
                                              const int* __restrict__ perm,
                                              const float* __restrict__ W,
                                              float* __restrict__ Out, int rows) {
    __shared__ float As[32][136];   // transposed A tile: As[k][r], pad for banks
    __shared__ float Ws[32][128];   // W tile: Ws[k][j]
    int tid = threadIdx.x;
    int rg = tid >> 4;   // 0..15 -> rows 8*rg
    int cg = tid & 15;   // 0..15 -> cols 8*cg
    int row0 = blockIdx.x * 128;
    float acc[8][8] = {};

    for (int kt = 0; kt < 128; kt += 32) {
        // stage A (128 rows x 32 k), transposed into As
        int lr = tid >> 3;          // 0..31
        int lk = (tid & 7) * 4;     // 0..28
        #pragma unroll
        for (int pass = 0; pass < 4; ++pass) {
            int r = row0 + pass * 32 + lr;
            float4 v = make_float4(0.f, 0.f, 0.f, 0.f);
            if (r < rows) {
                int sr = perm ? perm[r] : r;
                v = *(const float4*)(A + (size_t)sr * C + kt + lk);
            }
            As[lk + 0][pass * 32 + lr] = v.x;
            As[lk + 1][pass * 32 + lr] = v.y;
            As[lk + 2][pass * 32 + lr] = v.z;
            As[lk + 3][pass * 32 + lr] = v.w;
        }
        // stage W (32 k x 128 j)
        int wk = tid >> 3;          // 0..31
        #pragma unroll
        for (int pass = 0; pass < 4; ++pass) {
            int c = (tid & 7) * 4 + pass * 32;
            *(float4*)&Ws[wk][c] = *(const float4*)(W + (size_t)(kt + wk) * C + c);
        }
        __syncthreads();
        #pragma unroll
        for (int k = 0; k < 32; ++k) {
            float a[8], w[8];
            *(float4*)&a[0] = *(const float4*)&As[k][8 * rg];
            *(float4*)&a[4] = *(const float4*)&As[k][8 * rg + 4];
            *(float4*)&w[0] = *(const float4*)&Ws[k][8 * cg];
            *(float4*)&w[4] = *(const float4*)&Ws[k][8 * cg + 4];
            #pragma unroll
            for (int i = 0; i < 8; ++i)
                #pragma unroll
                for (int j = 0; j < 8; ++j)
                    acc[i][j] += a[i] * w[j];
        }
        __syncthreads();
    }
    #pragma unroll
    for (int i = 0; i < 8; ++i) {
        int r = row0 + 8 * rg + i;
        if (r < rows) {
            *(float4*)(Out + (size_t)r * C + 8 * cg)     = *(float4*)&acc[i][0];
            *(float4*)(Out + (size_t)r * C + 8 * cg + 4) = *(float4*)&acc[i][4];
        }
    }
}

// ---------------------------------------------------------------------------
// Aggregation over one chain's [NN,128] buffer:
// out[i] = sum_{e: dst=i} h[src_e] * w_e + h[i]*dinv[i]^2 + bias   (+PReLU)
// One wave per node; lane handles 2 channels (float2).
// ---------------------------------------------------------------------------

__global__ __launch_bounds__(256) void k_agg(const float* __restrict__ h,
                                             const float* __restrict__ dinv,
                                             const unsigned* __restrict__ off,
                                             const unsigned* __restrict__ csrc,
                                             const float* __restrict__ cw,
                                             const float* __restrict__ bias,
                                             const float* __restrict__ prelu,
                                             float* __restrict__ out) {
    int i    = (blockIdx.x * 256 + threadIdx.x) >> 6;   // global wave = node
    int lane = threadIdx.x & 63;
    if (i >= NN) return;
    float dv = dinv[i];
    float sn = dv * dv;

    float2 hv = ((const float2*)(h + (size_t)i * C))[lane];
    float ax = hv.x * sn, ay = hv.y * sn;

    unsigned p0 = off[i], p1 = off[i + 1];
    unsigned p = p0;
    if (p < p1) {
        unsigned s = csrc[p];
        float    w = cw[p];
        while (++p < p1) {
            unsigned s2 = csrc[p];
            float    w2 = cw[p];
            float2 v = ((const float2*)(h + (size_t)s * C))[lane];
            ax += v.x * w; ay += v.y * w;
            s = s2; w = w2;
        }
        float2 v = ((const float2*)(h + (size_t)s * C))[lane];
        ax += v.x * w; ay += v.y * w;
    }
    float2 bb = ((const float2*)bias)[lane];
    ax += bb.x; ay += bb.y;
    if (prelu) {
        float2 aa = ((const float2*)prelu)[lane];
        ax = (ax >= 0.f) ? ax : aa.x * ax;
        ay = (ay >= 0.f) ? ay : aa.y * ay;
    }
    float2 o; o.x = ax; o.y = ay;
    ((float2*)(out + (size_t)i * C))[lane] = o;
}

// ---------------------------------------------------------------------------
// summary = sigmoid(mean(pos_z, axis=0))
// ---------------------------------------------------------------------------

__global__ void k_sum(const float* __restrict__ pos, float* sumbuf) {
    int t = threadIdx.x;
    int c = t & 127;
    int half = t >> 7;
    float acc = 0.f;
    for (int r = blockIdx.x * 2 + half; r < NN; r += gridDim.x * 2)
        acc += pos[(size_t)r * C + c];
    atomicAdd(&sumbuf[c], acc);
}

__global__ void k_summary(const float* sumbuf, float* out) {
    int t = threadIdx.x;
    if (t < C) {
        float m = sumbuf[t] * (1.0f / (float)NN);
        out[t] = 1.0f / (1.0f + expf(-m));
    }
}

// ---------------------------------------------------------------------------
// q: Student's-t soft assignment. Block: 256 threads, 64 nodes, 4 threads/node.
// ---------------------------------------------------------------------------

__global__ __launch_bounds__(256) void k_q(const float* __restrict__ xo,
                                           const float* __restrict__ mu,
                                           float* __restrict__ qout) {
    __shared__ float sx[64][132];
    __shared__ float smu[KC][128];
    __shared__ float smun[KC];
    int tid = threadIdx.x;
    for (int idx = tid; idx < KC * 128; idx += 256)
        smu[idx >> 7][idx & 127] = mu[idx];
    __syncthreads();
    if (tid < KC) {
        float s = 0.f;
        #pragma unroll 4
        for (int j = 0; j < 128; ++j) { float m = smu[tid][j]; s += m * m; }
        smun[tid] = s;
    }
    int n0 = blockIdx.x * 64;
    for (int idx = tid; idx < 64 * 32; idx += 256) {
        int r = idx >> 5;
        int c = (idx & 31) * 4;
        int gr = n0 + r;
        float4 v = make_float4(0.f, 0.f, 0.f, 0.f);
        if (gr < NN) v = *(const float4*)(xo + (size_t)gr * C + c);
        *(float4*)&sx[r][c] = v;
    }
    __syncthreads();
    int lr = tid >> 2;
    int g  = tid & 3;            // cluster group: k = 5g..5g+4
    int node = n0 + lr;
    if (node < NN) {
        float ss = 0.f;
        #pragma unroll 8
        for (int j = 0; j < 128; ++j) { float x = sx[lr][j]; ss += x * x; }
        float qv[5]; float qs = 0.f;
        #pragma unroll
        for (int kk = 0; kk < 5; ++kk) {
            int k = g * 5 + kk;
            float dot = 0.f;
            #pragma unroll 8
            for (int j = 0; j < 128; ++j) dot += sx[lr][j] * smu[k][j];
            float d = ss + smun[k] - 2.0f * dot;
            d = fmaxf(d, 0.f);
            float q = 1.0f / (1.0f + d * 5.0f + 1e-8f);
            q = powf(q, 1.2f) * 0.5f;
            qv[kk] = q; qs += q;
        }
        qs += __shfl_xor(qs, 1, 64);
        qs += __shfl_xor(qs, 2, 64);
        float inv = 1.0f / qs;
        #pragma unroll
        for (int kk = 0; kk < 5; ++kk)
            qout[(size_t)node * KC + g * 5 + kk] = qv[kk] * inv;
    }
}

// ---------------------------------------------------------------------------
// launch
// ---------------------------------------------------------------------------

extern "C" void kernel_launch(void* const* d_in, const int* in_sizes, int n_in,
                              void* d_out, int out_size, void* d_ws, size_t ws_size,
                              hipStream_t stream) {
    const float* x    = (const float*)d_in[0];
    const int*   ei   = (const int*)d_in[1];    // int32 on device (harness converts)
    const float* ew   = (const float*)d_in[2];
    const int*   perm = (const int*)d_in[3];    // int32 on device
    const float* W1 = (const float*)d_in[4];  const float* b1 = (const float*)d_in[5];
    const float* W2 = (const float*)d_in[6];  const float* b2 = (const float*)d_in[7];
    const float* W3 = (const float*)d_in[8];  const float* b3 = (const float*)d_in[9];
    const float* W4 = (const float*)d_in[10]; const float* b4 = (const float*)d_in[11];
    const float* prelu_a = (const float*)d_in[12];
    const float* Wc = (const float*)d_in[13]; const float* bc = (const float*)d_in[14];
    const float* mu = (const float*)d_in[15];

    float* out     = (float*)d_out;
    float* pos_z   = out;                          // [N,128]
    float* neg_z   = out + (size_t)NN * C;         // [N,128]
    float* summary = out + (size_t)2 * NN * C;     // [128]
    float* xout    = summary + C;                  // [N,128]
    float* qout    = xout + (size_t)NN * C;        // [N,20]

    // workspace carve (~33 MB)
    char* w = (char*)d_ws;
    auto carve = [&](size_t bytes) { void* p = (void*)w; w += (bytes + 511) & ~(size_t)511; return p; };
    float*    deg    = (float*)carve((size_t)NN * 4);          // deg -> dinv in place
    unsigned* cnt    = (unsigned*)carve((size_t)(NN + 1) * 4); // hist -> offsets in place
    unsigned* cursor = (unsigned*)carve((size_t)NN * 4);
    unsigned* csrc   = (unsigned*)carve((size_t)EE * 4);
    float*    cw     = (float*)carve((size_t)EE * 4);
    float*    sumbuf = (float*)carve(128 * 4);
    float*    G      = (float*)carve((size_t)NN * C * 4);      // GEMM scratch [N,128]

    hipMemsetAsync(cnt, 0, (size_t)(NN + 1) * 4, stream);
    hipMemsetAsync(sumbuf, 0, 128 * 4, stream);

    int gN = (NN + 255) / 256, gE = (EE + 255) / 256;
    k_init_deg<<<gN, 256, 0, stream>>>(deg);
    k_deg_hist<<<gE, 256, 0, stream>>>(ei, ew, deg, cnt);
    k_dinv<<<gN, 256, 0, stream>>>(deg);                       // deg := dinv
    k_scan<<<1, 1024, 0, stream>>>(cnt, cursor);               // cnt := offsets
    k_fill<<<gE, 256, 0, stream>>>(ei, ew, deg, cursor, csrc, cw);

    int gG = (NN + 127) / 128, gA = (NN + 3) / 4;

    // pos chain: x -> pos_z   (H buffer = pos_z region of d_out)
    k_gemm<<<gG, 256, 0, stream>>>(x, nullptr, W1, G, NN);
    k_agg<<<gA, 256, 0, stream>>>(G, deg, cnt, csrc, cw, b1, nullptr, pos_z);
    k_gemm<<<gG, 256, 0, stream>>>(pos_z, nullptr, W2, G, NN);
    k_agg<<<gA, 256, 0, stream>>>(G, deg, cnt, csrc, cw, b2, nullptr, pos_z);
    k_gemm<<<gG, 256, 0, stream>>>(pos_z, nullptr, W3, G, NN);
    k_agg<<<gA, 256, 0, stream>>>(G, deg, cnt, csrc, cw, b3, nullptr, pos_z);
    k_gemm<<<gG, 256, 0, stream>>>(pos_z, nullptr, W4, G, NN);
    k_agg<<<gA, 256, 0, stream>>>(G, deg, cnt, csrc, cw, b4, prelu_a, pos_z);

    // neg chain: x[perm] -> neg_z
    k_gemm<<<gG, 256, 0, stream>>>(x, perm, W1, G, NN);
    k_agg<<<gA, 256, 0, stream>>>(G, deg, cnt, csrc, cw, b1, nullptr, neg_z);
    k_gemm<<<gG, 256, 0, stream>>>(neg_z, nullptr, W2, G, NN);
    k_agg<<<gA, 256, 0, stream>>>(G, deg, cnt, csrc, cw, b2, nullptr, neg_z);
    k_gemm<<<gG, 256, 0, stream>>>(neg_z, nullptr, W3, G, NN);
    k_agg<<<gA, 256, 0, stream>>>(G, deg, cnt, csrc, cw, b3, nullptr, neg_z);
    k_gemm<<<gG, 256, 0, stream>>>(neg_z, nullptr, W4, G, NN);
    k_agg<<<gA, 256, 0, stream>>>(G, deg, cnt, csrc, cw, b4, prelu_a, neg_z);

    // summary = sigmoid(mean(pos_z))
    k_sum<<<512, 256, 0, stream>>>(pos_z, sumbuf);
    k_summary<<<1, 128, 0, stream>>>(sumbuf, summary);

    // decoder conv: x_out = gcn_conv(pos_z, Wc, bc)
    k_gemm<<<gG, 256, 0, stream>>>(pos_z, nullptr, Wc, G, NN);
    k_agg<<<gA, 256, 0, stream>>>(G, deg, cnt, csrc, cw, bc, nullptr, xout);

    // q soft assignment
    k_q<<<(NN + 63) / 64, 256, 0, stream>>>(xout, mu, qout);
}

// Round 3
// 956.144 us; speedup vs baseline: 1.3063x; 1.3063x over previous
//
#include <hip/hip_runtime.h>
#include <hip/hip_bf16.h>

// Problem constants (from reference)
constexpr int NN = 50000;   // nodes
constexpr int EE = 800000;  // edges
constexpr int C  = 128;     // channels (IN == H == 128)
constexpr int KC = 20;      // clusters
constexpr int NB = (NN + 1023) / 1024;   // scan blocks (49)

typedef __attribute__((ext_vector_type(8))) short bf16x8;   // 8 bf16 (4 VGPRs)
typedef __attribute__((ext_vector_type(4))) float f32x4;

__device__ inline unsigned short f2bf(float f) {            // RN f32->bf16
    unsigned u = __float_as_uint(f);
    u += 0x7fff + ((u >> 16) & 1);
    return (unsigned short)(u >> 16);
}
__device__ inline float bf2f(unsigned short h) {
    return __uint_as_float(((unsigned)h) << 16);
}

// ---------------------------------------------------------------------------
// Graph preprocessing (int inputs are int32 on device)
// ---------------------------------------------------------------------------

__global__ void k_hist(const int* __restrict__ ei, unsigned* cnt) {
    int e = blockIdx.x * 256 + threadIdx.x;
    if (e >= EE) return;
    atomicAdd(&cnt[ei[EE + e]], 1u);
}

// 3-phase exclusive scan of cnt[NN] -> off[NN+1] (+ cursor copy)
__global__ __launch_bounds__(256) void k_scan1(const unsigned* __restrict__ cnt,
                                               unsigned* __restrict__ bsum) {
    __shared__ unsigned red[256];
    int b = blockIdx.x, t = threadIdx.x;
    int i0 = b * 1024 + t * 4;
    unsigned s = 0;
    #pragma unroll
    for (int j = 0; j < 4; ++j) { int i = i0 + j; s += (i < NN) ? cnt[i] : 0u; }
    red[t] = s; __syncthreads();
    for (int st = 128; st > 0; st >>= 1) { if (t < st) red[t] += red[t + st]; __syncthreads(); }
    if (t == 0) bsum[b] = red[0];
}

__global__ void k_scan2(unsigned* bsum, unsigned* total) {   // 1 block, 64 thr
    int t = threadIdx.x;
    unsigned v = (t < NB) ? bsum[t] : 0u;
    unsigned x = v;
    #pragma unroll
    for (int s = 1; s < 64; s <<= 1) { unsigned u = __shfl_up(x, s, 64); if (t >= s) x += u; }
    if (t < NB) bsum[t] = x - v;     // exclusive block offset
    if (t == 63) *total = x;
}

__global__ __launch_bounds__(256) void k_scan3(const unsigned* __restrict__ cnt,
                                               const unsigned* __restrict__ bsum,
                                               const unsigned* __restrict__ total,
                                               unsigned* __restrict__ off,
                                               unsigned* __restrict__ cursor) {
    __shared__ unsigned wred[4];
    int b = blockIdx.x, t = threadIdx.x, lane = t & 63, wv = t >> 6;
    int i0 = b * 1024 + t * 4;
    unsigned v[4]; unsigned s = 0;
    #pragma unroll
    for (int j = 0; j < 4; ++j) { int i = i0 + j; v[j] = (i < NN) ? cnt[i] : 0u; s += v[j]; }
    unsigned x = s;
    #pragma unroll
    for (int st = 1; st < 64; st <<= 1) { unsigned u = __shfl_up(x, st, 64); if (lane >= st) x += u; }
    if (lane == 63) wred[wv] = x;
    __syncthreads();
    unsigned woff = 0;
    for (int k = 0; k < 4; ++k) if (k < wv) woff += wred[k];
    unsigned excl = bsum[b] + woff + x - s;
    #pragma unroll
    for (int j = 0; j < 4; ++j) {
        int i = i0 + j;
        if (i < NN) { off[i] = excl; cursor[i] = excl; excl += v[j]; }
    }
    if (b == 0 && t == 0) off[NN] = *total;
}

// CSR fill with RAW edge weight (normalization applied later)
__global__ void k_fill(const int* __restrict__ ei, const float* __restrict__ ew,
                       unsigned* cursor, unsigned* __restrict__ csrc,
                       float* __restrict__ cw) {
    int e = blockIdx.x * 256 + threadIdx.x;
    if (e >= EE) return;
    int s = ei[e];
    int d = ei[EE + e];
    unsigned p = atomicAdd(&cursor[d], 1u);
    csrc[p] = (unsigned)s;
    cw[p]   = ew[e];
}

// deg[i] = 1 + sum(raw weights of row i); dinv = rsqrt (thread per node)
__global__ void k_dinv_csr(const unsigned* __restrict__ off,
                           const float* __restrict__ cw, float* __restrict__ dinv) {
    int i = blockIdx.x * 256 + threadIdx.x;
    if (i >= NN) return;
    unsigned p0 = off[i], p1 = off[i + 1];
    float s = 1.0f;                       // self-loop weight
    for (unsigned p = p0; p < p1; ++p) s += cw[p];
    dinv[i] = (s > 0.f) ? rsqrtf(s) : 0.f;
}

// cw[p] *= dinv[src]*dinv[dst]  (thread per node; dinv is L2-resident 200KB)
__global__ void k_scale(const unsigned* __restrict__ off, const unsigned* __restrict__ csrc,
                        const float* __restrict__ dinv, float* __restrict__ cw) {
    int i = blockIdx.x * 256 + threadIdx.x;
    if (i >= NN) return;
    float di = dinv[i];
    unsigned p0 = off[i], p1 = off[i + 1];
    for (unsigned p = p0; p < p1; ++p) cw[p] = dinv[csrc[p]] * cw[p] * di;
}

// ---------------------------------------------------------------------------
// Weight preconversion: W[128][128] f32 (k-major rows) -> Wt_hi/lo[col][k] bf16
// ---------------------------------------------------------------------------

__global__ void k_wsplit(const float* __restrict__ W, unsigned short* __restrict__ hi,
                         unsigned short* __restrict__ lo) {
    int idx = blockIdx.x * 256 + threadIdx.x;    // 0..16383
    int k = idx >> 7, j = idx & 127;
    float v = W[idx];
    unsigned short h = f2bf(v);
    hi[j * C + k] = h;
    lo[j * C + k] = f2bf(v - bf2f(h));
}

// ---------------------------------------------------------------------------
// MFMA GEMM: Out[rows,128] = A[sel(r),128] @ W[128,128], 3-term bf16x2 split.
// Block: 256 thr (4 waves), BM=64 rows, full N=128 (wave = 32-col strip).
// A staged in LDS as split-bf16 with XOR swizzle; B frags preloaded to VGPRs.
// ---------------------------------------------------------------------------

__global__ __launch_bounds__(256) void k_mm(const float* __restrict__ A,
                                            const int* __restrict__ perm,
                                            const unsigned short* __restrict__ Bh,
                                            const unsigned short* __restrict__ Bl,
                                            float* __restrict__ Out, int rows) {
    __shared__ unsigned short Ah[64 * 128];
    __shared__ unsigned short Al[64 * 128];
    int tid  = threadIdx.x;
    int lane = tid & 63;
    int wv   = tid >> 6;
    int row0 = blockIdx.x * 64;

    // stage A: f32 -> hi/lo bf16, swizzled LDS ( byte ^= (row&7)<<4 )
    {
        int r  = tid >> 2;                 // 0..63
        int c0 = (tid & 3) * 32;
        int gr = row0 + r;
        bool ok = gr < rows;
        int sr = ok ? (perm ? perm[gr] : gr) : 0;
        const float* src = A + (size_t)sr * C + c0;
        #pragma unroll
        for (int g = 0; g < 4; ++g) {
            float f[8];
            if (ok) {
                *(float4*)&f[0] = *(const float4*)(src + g * 8);
                *(float4*)&f[4] = *(const float4*)(src + g * 8 + 4);
            } else {
                #pragma unroll
                for (int j = 0; j < 8; ++j) f[j] = 0.f;
            }
            union { unsigned short u[8]; uint4 v; } ph, pl;
            #pragma unroll
            for (int j = 0; j < 8; ++j) {
                unsigned short h = f2bf(f[j]);
                ph.u[j] = h;
                pl.u[j] = f2bf(f[j] - bf2f(h));
            }
            int k = c0 + g * 8;
            int byte = (r * 256 + k * 2) ^ ((r & 7) << 4);
            *(uint4*)((char*)Ah + byte) = ph.v;
            *(uint4*)((char*)Al + byte) = pl.v;
        }
    }

    // B fragments: lane reads Wt[col][k0..k0+8) = W^T, same frag layout as A
    bf16x8 bh[2][4], bl[2][4];
    {
        #pragma unroll
        for (int cf = 0; cf < 2; ++cf) {
            int col = wv * 32 + cf * 16 + (lane & 15);
            #pragma unroll
            for (int kt = 0; kt < 4; ++kt) {
                int k = kt * 32 + (lane >> 4) * 8;
                bh[cf][kt] = *(const bf16x8*)(Bh + (size_t)col * C + k);
                bl[cf][kt] = *(const bf16x8*)(Bl + (size_t)col * C + k);
            }
        }
    }

    __syncthreads();

    f32x4 zero = {0.f, 0.f, 0.f, 0.f};
    f32x4 acc[4][2];
    #pragma unroll
    for (int rf = 0; rf < 4; ++rf)
        #pragma unroll
        for (int cf = 0; cf < 2; ++cf) acc[rf][cf] = zero;

    #pragma unroll
    for (int rf = 0; rf < 4; ++rf) {
        int row = rf * 16 + (lane & 15);
        #pragma unroll
        for (int kt = 0; kt < 4; ++kt) {
            int k = kt * 32 + (lane >> 4) * 8;
            int byte = (row * 256 + k * 2) ^ ((row & 7) << 4);
            bf16x8 ah = *(const bf16x8*)((const char*)Ah + byte);
            bf16x8 al = *(const bf16x8*)((const char*)Al + byte);
            #pragma unroll
            for (int cf = 0; cf < 2; ++cf) {
                acc[rf][cf] = __builtin_amdgcn_mfma_f32_16x16x32_bf16(ah, bh[cf][kt], acc[rf][cf], 0, 0, 0);
                acc[rf][cf] = __builtin_amdgcn_mfma_f32_16x16x32_bf16(al, bh[cf][kt], acc[rf][cf], 0, 0, 0);
                acc[rf][cf] = __builtin_amdgcn_mfma_f32_16x16x32_bf16(ah, bl[cf][kt], acc[rf][cf], 0, 0, 0);
            }
        }
    }

    // epilogue: C/D layout col=lane&15, row=(lane>>4)*4+q (m89-verified)
    #pragma unroll
    for (int rf = 0; rf < 4; ++rf) {
        #pragma unroll
        for (int cf = 0; cf < 2; ++cf) {
            int col = wv * 32 + cf * 16 + (lane & 15);
            #pragma unroll
            for (int q = 0; q < 4; ++q) {
                int row = row0 + rf * 16 + (lane >> 4) * 4 + q;
                if (row < rows) Out[(size_t)row * C + col] = acc[rf][cf][q];
            }
        }
    }
}

// ---------------------------------------------------------------------------
// Aggregation: out[i] = sum_{e:dst=i} h[src_e]*w_e + h[i]*dinv[i]^2 + bias (+PReLU)
// One wave per node; lane = 2 channels; 2-edge unroll for MLP.
// ---------------------------------------------------------------------------

__global__ __launch_bounds__(256) void k_agg(const float* __restrict__ h,
                                             const float* __restrict__ dinv,
                                             const unsigned* __restrict__ off,
                                             const unsigned* __restrict__ csrc,
                                             const float* __restrict__ cw,
                                             const float* __restrict__ bias,
                                             const float* __restrict__ prelu,
                                             float* __restrict__ out) {
    int i    = (blockIdx.x * 256 + threadIdx.x) >> 6;
    int lane = threadIdx.x & 63;
    if (i >= NN) return;
    float dv = dinv[i];
    float sn = dv * dv;
    float2 hv = ((const float2*)(h + (size_t)i * C))[lane];
    float ax = hv.x * sn, ay = hv.y * sn;
    float bx = 0.f, by = 0.f;
    unsigned p0 = off[i], p1 = off[i + 1];
    unsigned p = p0;
    for (; p + 2 <= p1; p += 2) {
        unsigned s0 = csrc[p], s1 = csrc[p + 1];
        float w0 = cw[p], w1 = cw[p + 1];
        float2 v0 = ((const float2*)(h + (size_t)s0 * C))[lane];
        float2 v1 = ((const float2*)(h + (size_t)s1 * C))[lane];
        ax += v0.x * w0; ay += v0.y * w0;
        bx += v1.x * w1; by += v1.y * w1;
    }
    if (p < p1) {
        unsigned s0 = csrc[p]; float w0 = cw[p];
        float2 v0 = ((const float2*)(h + (size_t)s0 * C))[lane];
        ax += v0.x * w0; ay += v0.y * w0;
    }
    ax += bx; ay += by;
    float2 bb = ((const float2*)bias)[lane];
    ax += bb.x; ay += bb.y;
    if (prelu) {
        float2 aa = ((const float2*)prelu)[lane];
        ax = (ax >= 0.f) ? ax : aa.x * ax;
        ay = (ay >= 0.f) ? ay : aa.y * ay;
    }
    ((float2*)(out + (size_t)i * C))[lane] = make_float2(ax, ay);
}

// ---------------------------------------------------------------------------
// summary = sigmoid(mean(pos_z, axis=0))
// ---------------------------------------------------------------------------

__global__ __launch_bounds__(256) void k_sum(const float* __restrict__ pos, float* sumbuf) {
    __shared__ float red[256];
    int t = threadIdx.x;
    int c = t & 127;
    int half = t >> 7;
    float acc = 0.f;
    for (int r = blockIdx.x * 2 + half; r < NN; r += gridDim.x * 2)
        acc += pos[(size_t)r * C + c];
    red[t] = acc;
    __syncthreads();
    if (half == 0) atomicAdd(&sumbuf[c], acc + red[t + 128]);
}

__global__ void k_summary(const float* sumbuf, float* out) {
    int t = threadIdx.x;
    if (t < C) {
        float m = sumbuf[t] * (1.0f / (float)NN);
        out[t] = 1.0f / (1.0f + expf(-m));
    }
}

// ---------------------------------------------------------------------------
// q: Student's-t soft assignment. 256 thr: 64 nodes, 4 threads/node.
// ---------------------------------------------------------------------------

__global__ __launch_bounds__(256) void k_q(const float* __restrict__ xo,
                                           const float* __restrict__ mu,
                                           float* __restrict__ qout) {
    __shared__ float sx[64][132];
    __shared__ float smu[KC][128];
    __shared__ float smun[KC];
    int tid = threadIdx.x;
    for (int idx = tid; idx < KC * 128; idx += 256)
        smu[idx >> 7][idx & 127] = mu[idx];
    __syncthreads();
    if (tid < KC) {
        float s = 0.f;
        #pragma unroll 4
        for (int j = 0; j < 128; ++j) { float m = smu[tid][j]; s += m * m; }
        smun[tid] = s;
    }
    int n0 = blockIdx.x * 64;
    for (int idx = tid; idx < 64 * 32; idx += 256) {
        int r = idx >> 5;
        int c = (idx & 31) * 4;
        int gr = n0 + r;
        float4 v = make_float4(0.f, 0.f, 0.f, 0.f);
        if (gr < NN) v = *(const float4*)(xo + (size_t)gr * C + c);
        *(float4*)&sx[r][c] = v;
    }
    __syncthreads();
    int lr = tid >> 2;
    int g  = tid & 3;
    int node = n0 + lr;
    if (node < NN) {
        float ss = 0.f;
        #pragma unroll 8
        for (int j = 0; j < 128; ++j) { float x = sx[lr][j]; ss += x * x; }
        float qv[5]; float qs = 0.f;
        #pragma unroll
        for (int kk = 0; kk < 5; ++kk) {
            int k = g * 5 + kk;
            float dot = 0.f;
            #pragma unroll 8
            for (int j = 0; j < 128; ++j) dot += sx[lr][j] * smu[k][j];
            float d = ss + smun[k] - 2.0f * dot;
            d = fmaxf(d, 0.f);
            float q = 1.0f / (1.0f + d * 5.0f + 1e-8f);
            q = powf(q, 1.2f) * 0.5f;
            qv[kk] = q; qs += q;
        }
        qs += __shfl_xor(qs, 1, 64);
        qs += __shfl_xor(qs, 2, 64);
        float inv = 1.0f / qs;
        #pragma unroll
        for (int kk = 0; kk < 5; ++kk)
            qout[(size_t)node * KC + g * 5 + kk] = qv[kk] * inv;
    }
}

// ---------------------------------------------------------------------------
// launch
// ---------------------------------------------------------------------------

extern "C" void kernel_launch(void* const* d_in, const int* in_sizes, int n_in,
                              void* d_out, int out_size, void* d_ws, size_t ws_size,
                              hipStream_t stream) {
    const float* x    = (const float*)d_in[0];
    const int*   ei   = (const int*)d_in[1];
    const float* ew   = (const float*)d_in[2];
    const int*   perm = (const int*)d_in[3];
    const float* W1 = (const float*)d_in[4];  const float* b1 = (const float*)d_in[5];
    const float* W2 = (const float*)d_in[6];  const float* b2 = (const float*)d_in[7];
    const float* W3 = (const float*)d_in[8];  const float* b3 = (const float*)d_in[9];
    const float* W4 = (const float*)d_in[10]; const float* b4 = (const float*)d_in[11];
    const float* prelu_a = (const float*)d_in[12];
    const float* Wc = (const float*)d_in[13]; const float* bc = (const float*)d_in[14];
    const float* mu = (const float*)d_in[15];

    float* out     = (float*)d_out;
    float* pos_z   = out;                          // [N,128]
    float* neg_z   = out + (size_t)NN * C;         // [N,128]
    float* summary = out + (size_t)2 * NN * C;     // [128]
    float* xout    = summary + C;                  // [N,128]
    float* qout    = xout + (size_t)NN * C;        // [N,20]

    // workspace carve (~33.3 MB)
    char* w = (char*)d_ws;
    auto carve = [&](size_t bytes) { void* p = (void*)w; w += (bytes + 511) & ~(size_t)511; return p; };
    float*          dinv   = (float*)carve((size_t)NN * 4);
    unsigned*       cnt    = (unsigned*)carve((size_t)(NN + 1) * 4);  // -> off in place
    unsigned*       cursor = (unsigned*)carve((size_t)NN * 4);
    unsigned*       bsum   = (unsigned*)carve(256 * 4);
    unsigned*       total  = (unsigned*)carve(64);
    unsigned*       csrc   = (unsigned*)carve((size_t)EE * 4);
    float*          cw     = (float*)carve((size_t)EE * 4);
    float*          sumbuf = (float*)carve(512);
    unsigned short* wt     = (unsigned short*)carve((size_t)5 * 2 * C * C * 2); // 5 mats hi+lo
    float*          G      = (float*)carve((size_t)NN * C * 4);       // GEMM scratch

    unsigned short* Wh[5], *Wl[5];
    const float* Wsrc[5] = {W1, W2, W3, W4, Wc};
    for (int m = 0; m < 5; ++m) {
        Wh[m] = wt + (size_t)(2 * m) * C * C;
        Wl[m] = wt + (size_t)(2 * m + 1) * C * C;
    }

    hipMemsetAsync(cnt, 0, (size_t)(NN + 1) * 4, stream);
    hipMemsetAsync(sumbuf, 0, 512, stream);

    int gE = (EE + 255) / 256, gN = (NN + 255) / 256;

    // graph build
    k_hist <<<gE, 256, 0, stream>>>(ei, cnt);
    k_scan1<<<NB, 256, 0, stream>>>(cnt, bsum);
    k_scan2<<<1, 64, 0, stream>>>(bsum, total);
    k_scan3<<<NB, 256, 0, stream>>>(cnt, bsum, total, cnt, cursor);   // cnt := off
    k_fill <<<gE, 256, 0, stream>>>(ei, ew, cursor, csrc, cw);
    k_dinv_csr<<<gN, 256, 0, stream>>>(cnt, cw, dinv);
    k_scale<<<gN, 256, 0, stream>>>(cnt, csrc, dinv, cw);

    // weight split/transpose (5 mats)
    for (int m = 0; m < 5; ++m)
        k_wsplit<<<64, 256, 0, stream>>>(Wsrc[m], Wh[m], Wl[m]);

    int gM = (NN + 63) / 64, gA = (NN + 3) / 4;

    // pos chain
    k_mm <<<gM, 256, 0, stream>>>(x, nullptr, Wh[0], Wl[0], G, NN);
    k_agg<<<gA, 256, 0, stream>>>(G, dinv, cnt, csrc, cw, b1, nullptr, pos_z);
    k_mm <<<gM, 256, 0, stream>>>(pos_z, nullptr, Wh[1], Wl[1], G, NN);
    k_agg<<<gA, 256, 0, stream>>>(G, dinv, cnt, csrc, cw, b2, nullptr, pos_z);
    k_mm <<<gM, 256, 0, stream>>>(pos_z, nullptr, Wh[2], Wl[2], G, NN);
    k_agg<<<gA, 256, 0, stream>>>(G, dinv, cnt, csrc, cw, b3, nullptr, pos_z);
    k_mm <<<gM, 256, 0, stream>>>(pos_z, nullptr, Wh[3], Wl[3], G, NN);
    k_agg<<<gA, 256, 0, stream>>>(G, dinv, cnt, csrc, cw, b4, prelu_a, pos_z);

    // neg chain (x[perm] input)
    k_mm <<<gM, 256, 0, stream>>>(x, perm, Wh[0], Wl[0], G, NN);
    k_agg<<<gA, 256, 0, stream>>>(G, dinv, cnt, csrc, cw, b1, nullptr, neg_z);
    k_mm <<<gM, 256, 0, stream>>>(neg_z, nullptr, Wh[1], Wl[1], G, NN);
    k_agg<<<gA, 256, 0, stream>>>(G, dinv, cnt, csrc, cw, b2, nullptr, neg_z);
    k_mm <<<gM, 256, 0, stream>>>(neg_z, nullptr, Wh[2], Wl[2], G, NN);
    k_agg<<<gA, 256, 0, stream>>>(G, dinv, cnt, csrc, cw, b3, nullptr, neg_z);
    k_mm <<<gM, 256, 0, stream>>>(neg_z, nullptr, Wh[3], Wl[3], G, NN);
    k_agg<<<gA, 256, 0, stream>>>(G, dinv, cnt, csrc, cw, b4, prelu_a, neg_z);

    // summary
    k_sum<<<256, 256, 0, stream>>>(pos_z, sumbuf);
    k_summary<<<1, 128, 0, stream>>>(sumbuf, summary);

    // decoder conv
    k_mm <<<gM, 256, 0, stream>>>(pos_z, nullptr, Wh[4], Wl[4], G, NN);
    k_agg<<<gA, 256, 0, stream>>>(G, dinv, cnt, csrc, cw, bc, nullptr, xout);

    // q soft assignment
    k_q<<<(NN + 63) / 64, 256, 0, stream>>>(xout, mu, qout);
}